// Round 10
// baseline (1692.871 us; speedup 1.0000x reference)
//
#include <hip/hip_runtime.h>
#include <hip/hip_bf16.h>
#include <math.h>

#define KN 64
#define HO 124
#define KP 104
#define NOUT (128LL * 124 * 124 * 64)  // 125,960,192
#define NG 31                          // ho-groups (of 4) per image
#define NCONV (128 * NG)               // 3968 conv blocks

// INSTRUMENTATION ROUND: in-kernel repeats so single dispatches exceed the
// harness's ~590us fill kernels and surface in rocprof top-5. Idempotent.
#define REP_CONV 8
#define REP_SIG 8
#define REP_SSN 50

// ws layout: ssn 7,872,512 B | w_bf 13,312 B | sp 256 B
#define WS_SSN_OFF 0ULL
#define WS_WBF_OFF 7872512ULL
#define WS_SP_OFF 7885824ULL

typedef short bfrag8 __attribute__((ext_vector_type(8)));  // 8 bf16
typedef float ffrag4 __attribute__((ext_vector_type(4)));  // 4 f32

__device__ __forceinline__ unsigned short f2bf(float f) {
    union { float f; unsigned u; } x;
    x.f = f;
    unsigned r = x.u + 0x7fffu + ((x.u >> 16) & 1u);
    return (unsigned short)(r >> 16);
}
__device__ __forceinline__ unsigned pack2(float a, float b) {
    return (unsigned)f2bf(a) | ((unsigned)f2bf(b) << 16);
}

// XOR-swizzled byte offset into s_im: [row][wo][16 bf16] = 32 B per (row,wo).
__device__ __forceinline__ int im_off(int row, int wo, int half) {
    return (((row * 128 + wo) * 32) + half * 16) ^ (((wo >> 2) & 7) << 4);
}

// -------- one-time prep: weight transpose->bf16 + softplus + KL scalar -----
__global__ void prep_kernel(const float* __restrict__ w_mu,
                            const float* __restrict__ w_sigma,
                            unsigned short* __restrict__ w_bf,
                            float* __restrict__ sp_out,
                            float* __restrict__ out_kl) {
    const int tid = threadIdx.x;       // 256
    const int n = tid >> 2;            // 64 rows, 4 threads each
    const int kbase = (tid & 3) * 26;  // 4*26 = 104
#pragma unroll
    for (int kk = 0; kk < 26; ++kk) {
        const int k = kbase + kk;
        float v = 0.f;
        if (k < 80) {
            const int r = k >> 4, t = k & 15;
            if (t < 15) v = w_mu[(r * 15 + t) * KN + n];
        }
        w_bf[n * KP + k] = f2bf(v);
    }
    if (tid < KN) sp_out[tid] = log1pf(expf(w_sigma[tid]));

    if (tid < 64) {
        float s = 0.f;
#pragma unroll
        for (int i = 0; i < 75; ++i) {
            float m = w_mu[i * KN + tid];
            s = fmaf(m, m, s);
        }
        float lv = w_sigma[tid];
        float sp = log1pf(expf(lv));
        float val = 1.0f + lv - sp - s * (1.0f / 75.0f);
#pragma unroll
        for (int off = 32; off > 0; off >>= 1) val += __shfl_down(val, off);
        if (tid == 0) {
            float kl = -(val / 64.0f);
            if (isnan(kl) || isinf(kl)) kl = 1e-5f;
            out_kl[0] = kl;
        }
    }
}

// ---------------- ssn prepass: patch sum-of-squares / 75 (x REP_SSN) -------
__global__ void ssn_kernel(const float* __restrict__ mu_in,
                           float* __restrict__ ssn_ws) {
    __shared__ __align__(16) float s_cs[8 * 128];
    const int bid = blockIdx.x;
    const int b = bid / NG;
    const int ho0 = (bid % NG) * 4;
    const int tid = threadIdx.x;

#pragma unroll 1
    for (int rep = 0; rep < REP_SSN; ++rep) {
        if (rep) __syncthreads();  // WAR on s_cs across reps
        {
            const int r = tid >> 5;          // 0..7
            const int c4 = (tid & 31) << 2;  // 0..124
            const float* p =
                mu_in + ((size_t)(b * 128 + ho0 + r) * 384 + c4 * 3);
            float4 f0 = reinterpret_cast<const float4*>(p)[0];
            float4 f1 = reinterpret_cast<const float4*>(p)[1];
            float4 f2 = reinterpret_cast<const float4*>(p)[2];
            float4 cs;
            cs.x = f0.x * f0.x + f0.y * f0.y + f0.z * f0.z;
            cs.y = f0.w * f0.w + f1.x * f1.x + f1.y * f1.y;
            cs.z = f1.z * f1.z + f1.w * f1.w + f2.x * f2.x;
            cs.w = f2.y * f2.y + f2.z * f2.z + f2.w * f2.w;
            *reinterpret_cast<float4*>(&s_cs[r * 128 + c4]) = cs;
        }
        __syncthreads();

#pragma unroll
        for (int it = 0; it < 2; ++it) {
            const int idx = tid + it * 256;
            const int hl = idx >> 7, wo = idx & 127;
            if (wo < HO) {
                float s = 0.f;
#pragma unroll
                for (int r = 0; r < 5; ++r) {
                    const float* cr = &s_cs[(hl + r) * 128 + wo];
                    s += cr[0] + cr[1] + cr[2] + cr[3] + cr[4];
                }
                ssn_ws[((size_t)(b * HO) + ho0 + hl) * HO + wo] =
                    s * (1.0f / 75.0f);
            }
        }
    }
}

// ---------------- sigma streaming kernel (fill-like, x REP_SIG) ------------
__global__ __launch_bounds__(256) void sigma_kernel(
    const float* __restrict__ ssn_ws, const float* __restrict__ sp_in,
    float4* __restrict__ sig_out) {
    const long long TOT = 128LL * 124 * 124 * 16;  // 31,490,048 chunks
    const long long NT = (long long)gridDim.x * 256;
    const long long g0 = (long long)blockIdx.x * 256 + threadIdx.x;
    const float4 sp4 = reinterpret_cast<const float4*>(sp_in)[g0 & 15];

#pragma unroll 1
    for (int rep = 0; rep < REP_SIG; ++rep) {
        long long g = g0;
        for (; g + 3 * NT < TOT; g += 4 * NT) {
            const float s0 = ssn_ws[g >> 4];
            const float s1 = ssn_ws[(g + NT) >> 4];
            const float s2 = ssn_ws[(g + 2 * NT) >> 4];
            const float s3 = ssn_ws[(g + 3 * NT) >> 4];
            sig_out[g] =
                make_float4(sp4.x * s0, sp4.y * s0, sp4.z * s0, sp4.w * s0);
            sig_out[g + NT] =
                make_float4(sp4.x * s1, sp4.y * s1, sp4.z * s1, sp4.w * s1);
            sig_out[g + 2 * NT] =
                make_float4(sp4.x * s2, sp4.y * s2, sp4.z * s2, sp4.w * s2);
            sig_out[g + 3 * NT] =
                make_float4(sp4.x * s3, sp4.y * s3, sp4.z * s3, sp4.w * s3);
        }
        for (; g < TOT; g += NT) {
            const float s = ssn_ws[g >> 4];
            sig_out[g] = make_float4(sp4.x * s, sp4.y * s, sp4.z * s, sp4.w * s);
        }
    }
}

// im2col fill: wave-uniform alignment class. OFF = (3*wo) mod 4, constexpr.
template <int OFF>
__device__ __forceinline__ void im_fill(const float* __restrict__ mu_in,
                                        unsigned short* s_im, int b, int ho0,
                                        int lane, int wo) {
#pragma unroll
    for (int j = 0; j < 4; ++j) {
        const int row = ((lane >> 5) << 2) + j;  // 0..7
        uint4* dst0 =
            reinterpret_cast<uint4*>((char*)s_im + im_off(row, wo, 0));
        uint4* dst1 =
            reinterpret_cast<uint4*>((char*)s_im + im_off(row, wo, 1));
        if (wo >= 124) {
            *dst0 = make_uint4(0u, 0u, 0u, 0u);
            *dst1 = make_uint4(0u, 0u, 0u, 0u);
            continue;
        }
        const float* p =
            mu_in + ((size_t)(b * 128 + ho0 + row) * 384 + wo * 3 - OFF);
        float w[20];
        float4 f;
        f = reinterpret_cast<const float4*>(p)[0];
        w[0] = f.x; w[1] = f.y; w[2] = f.z; w[3] = f.w;
        f = reinterpret_cast<const float4*>(p)[1];
        w[4] = f.x; w[5] = f.y; w[6] = f.z; w[7] = f.w;
        f = reinterpret_cast<const float4*>(p)[2];
        w[8] = f.x; w[9] = f.y; w[10] = f.z; w[11] = f.w;
        f = reinterpret_cast<const float4*>(p)[3];
        w[12] = f.x; w[13] = f.y; w[14] = f.z; w[15] = f.w;
        if (OFF >= 2) {
            f = reinterpret_cast<const float4*>(p)[4];
            w[16] = f.x; w[17] = f.y; w[18] = f.z; w[19] = f.w;
        } else {
            w[16] = 0.f; w[17] = 0.f; w[18] = 0.f; w[19] = 0.f;
        }
        unsigned u0 = pack2(w[OFF + 0], w[OFF + 1]);
        unsigned u1 = pack2(w[OFF + 2], w[OFF + 3]);
        unsigned u2 = pack2(w[OFF + 4], w[OFF + 5]);
        unsigned u3 = pack2(w[OFF + 6], w[OFF + 7]);
        unsigned u4 = pack2(w[OFF + 8], w[OFF + 9]);
        unsigned u5 = pack2(w[OFF + 10], w[OFF + 11]);
        unsigned u6 = pack2(w[OFF + 12], w[OFF + 13]);
        unsigned u7 = pack2(w[OFF + 14], 0.0f);  // t=15: weight is zero
        *dst0 = make_uint4(u0, u1, u2, u3);
        *dst1 = make_uint4(u4, u5, u6, u7);
    }
}

// ---------------- conv kernel: mu only (R6 structure, x REP_CONV) ----------
__global__ __launch_bounds__(256, 4) void conv_mu_kernel(
    const float* __restrict__ mu_in,
    const unsigned short* __restrict__ w_bf,
    float* __restrict__ mu_out) {

    __shared__ __align__(16) unsigned short s_im[8 * 128 * 16];  // 32 KB

    const int bid = blockIdx.x;
    const int b = bid / NG;
    const int ho0 = (bid % NG) * 4;
    const int tid = threadIdx.x;
    const int lane = tid & 63;
    const int wid = tid >> 6;
    const int llo = lane & 15;
    const int lhi = lane >> 4;

    // weights -> regs (L2-hot)
    bfrag8 afr[4][3];
#pragma unroll
    for (int mt = 0; mt < 4; ++mt)
#pragma unroll
        for (int ks = 0; ks < 3; ++ks)
            afr[mt][ks] = *reinterpret_cast<const bfrag8*>(
                &w_bf[(mt * 16 + llo) * KP + ks * 32 + lhi * 8]);

#pragma unroll 1
    for (int rep = 0; rep < REP_CONV; ++rep) {
        if (rep) __syncthreads();  // WAR on s_im across reps
        // im2col (each wave owns one wo mod-4 class)
        {
            const int wo = wid + ((lane & 31) << 2);
            switch (wid) {  // OFF = (3*class) mod 4
                case 0: im_fill<0>(mu_in, s_im, b, ho0, lane, wo); break;
                case 1: im_fill<3>(mu_in, s_im, b, ho0, lane, wo); break;
                case 2: im_fill<2>(mu_in, s_im, b, ho0, lane, wo); break;
                default: im_fill<1>(mu_in, s_im, b, ho0, lane, wo); break;
            }
        }
        __syncthreads();

#pragma unroll
        for (int hl = 0; hl < 4; ++hl) {
            ffrag4 acc[2][4];
#pragma unroll
            for (int nt = 0; nt < 2; ++nt)
#pragma unroll
                for (int mt = 0; mt < 4; ++mt)
                    acc[nt][mt] = (ffrag4){0.f, 0.f, 0.f, 0.f};

#pragma unroll
            for (int nt = 0; nt < 2; ++nt) {
                const int wo = (wid * 2 + nt) * 16 + llo;
#pragma unroll
                for (int ks = 0; ks < 3; ++ks) {
                    const int k0 = ks * 32 + lhi * 8;
                    const int r = k0 >> 4;  // 0..5 (5 => k>=80: zero operand)
                    bfrag8 bfr = (bfrag8){0, 0, 0, 0, 0, 0, 0, 0};
                    if (r < 5) {
                        bfr = *reinterpret_cast<const bfrag8*>(
                            (char*)s_im + im_off(hl + r, wo, (k0 & 15) >> 3));
                    }
#pragma unroll
                    for (int mt = 0; mt < 4; ++mt)
                        acc[nt][mt] = __builtin_amdgcn_mfma_f32_16x16x32_bf16(
                            afr[mt][ks], bfr, acc[nt][mt], 0, 0, 0);
                }
            }

            const size_t orow =
                (size_t)(b * HO + ho0 + hl) * (size_t)(HO * KN);
#pragma unroll
            for (int nt = 0; nt < 2; ++nt) {
                const int wo = (wid * 2 + nt) * 16 + llo;
                if (wo < HO) {
                    const size_t obase = orow + (size_t)wo * KN;
#pragma unroll
                    for (int mt = 0; mt < 4; ++mt) {
                        const int knb = mt * 16 + lhi * 4;
                        *reinterpret_cast<float4*>(&mu_out[obase + knb]) =
                            make_float4(acc[nt][mt][0], acc[nt][mt][1],
                                        acc[nt][mt][2], acc[nt][mt][3]);
                    }
                }
            }
        }
    }
}

extern "C" void kernel_launch(void* const* d_in, const int* in_sizes, int n_in,
                              void* d_out, int out_size, void* d_ws,
                              size_t ws_size, hipStream_t stream) {
    const float* mu_in = (const float*)d_in[0];
    const float* w_mu = (const float*)d_in[1];
    const float* w_sigma = (const float*)d_in[2];
    float* out = (float*)d_out;

    float* mu_out = out;             // N floats
    float* sig_out = out + NOUT;     // N floats
    float* kl_out = out + 2 * NOUT;  // 1 float

    char* ws = (char*)d_ws;
    float* ssn_ws = (float*)(ws + WS_SSN_OFF);
    unsigned short* w_bf = (unsigned short*)(ws + WS_WBF_OFF);
    float* sp_ws = (float*)(ws + WS_SP_OFF);

    prep_kernel<<<1, 256, 0, stream>>>(w_mu, w_sigma, w_bf, sp_ws, kl_out);
    ssn_kernel<<<128 * NG, 256, 0, stream>>>(mu_in, ssn_ws);
    conv_mu_kernel<<<NCONV, 256, 0, stream>>>(mu_in, w_bf, mu_out);
    sigma_kernel<<<2048, 256, 0, stream>>>(ssn_ws, sp_ws, (float4*)sig_out);
}

// Round 11
// 302.645 us; speedup vs baseline: 5.5936x; 5.5936x over previous
//
#include <hip/hip_runtime.h>
#include <hip/hip_bf16.h>
#include <math.h>

#define KN 64
#define HO 124
#define KP 104
#define NOUT (128LL * 124 * 124 * 64)  // 125,960,192
#define NG 31                          // ho-groups (of 4) per image
#define NCONV (128 * NG)               // 3968 blocks (= 8 * 496)

// ws layout: w_bf 13,312 B | sp 256 B
#define WS_WBF_OFF 0ULL
#define WS_SP_OFF 13312ULL

typedef short bfrag8 __attribute__((ext_vector_type(8)));  // 8 bf16
typedef float ffrag4 __attribute__((ext_vector_type(4)));  // 4 f32

__device__ __forceinline__ unsigned short f2bf(float f) {
    union { float f; unsigned u; } x;
    x.f = f;
    unsigned r = x.u + 0x7fffu + ((x.u >> 16) & 1u);
    return (unsigned short)(r >> 16);
}
__device__ __forceinline__ unsigned pack2(float a, float b) {
    return (unsigned)f2bf(a) | ((unsigned)f2bf(b) << 16);
}

// bijective XCD swizzle (3968 % 8 == 0): chunk of 496 consecutive ids per XCD
__device__ __forceinline__ int xcd_swz(int bid) {
    return (bid & 7) * (NCONV / 8) + (bid >> 3);
}

// XOR-swizzled byte offset into s_im: [row][wo][16 bf16] = 32 B per (row,wo).
__device__ __forceinline__ int im_off(int row, int wo, int half) {
    return (((row * 128 + wo) * 32) + half * 16) ^ (((wo >> 2) & 7) << 4);
}

// -------- one-time prep: weight transpose->bf16 + softplus + KL scalar -----
__global__ void prep_kernel(const float* __restrict__ w_mu,
                            const float* __restrict__ w_sigma,
                            unsigned short* __restrict__ w_bf,
                            float* __restrict__ sp_out,
                            float* __restrict__ out_kl) {
    const int tid = threadIdx.x;       // 256
    const int n = tid >> 2;            // 64 rows, 4 threads each
    const int kbase = (tid & 3) * 26;  // 4*26 = 104
#pragma unroll
    for (int kk = 0; kk < 26; ++kk) {
        const int k = kbase + kk;
        float v = 0.f;
        if (k < 80) {
            const int r = k >> 4, t = k & 15;
            if (t < 15) v = w_mu[(r * 15 + t) * KN + n];
        }
        w_bf[n * KP + k] = f2bf(v);
    }
    if (tid < KN) sp_out[tid] = log1pf(expf(w_sigma[tid]));

    if (tid < 64) {
        float s = 0.f;
#pragma unroll
        for (int i = 0; i < 75; ++i) {
            float m = w_mu[i * KN + tid];
            s = fmaf(m, m, s);
        }
        float lv = w_sigma[tid];
        float sp = log1pf(expf(lv));
        float val = 1.0f + lv - sp - s * (1.0f / 75.0f);
#pragma unroll
        for (int off = 32; off > 0; off >>= 1) val += __shfl_down(val, off);
        if (tid == 0) {
            float kl = -(val / 64.0f);
            if (isnan(kl) || isinf(kl)) kl = 1e-5f;
            out_kl[0] = kl;
        }
    }
}

// ---- conv staging: issue ALL row loads first, then pack+ds_write ----------
// (R10 PMC: VGPR=64 showed the compiler serialized load->pack->store per row,
// paying 4x load latency in the store-free head. Load-first costs ~80 VGPR.)
template <int OFF>
__device__ __forceinline__ void im_stage(const float* __restrict__ mu_in,
                                         unsigned short* s_im, int b, int ho0,
                                         int lane, int wo) {
    const int rb = (lane >> 5) << 2;  // 0 or 4
    float4 f[4][5];
    if (wo < 124) {
#pragma unroll
        for (int j = 0; j < 4; ++j) {
            const float4* p = reinterpret_cast<const float4*>(
                mu_in + ((size_t)(b * 128 + ho0 + rb + j) * 384 + wo * 3 - OFF));
#pragma unroll
            for (int q = 0; q < 4; ++q) f[j][q] = p[q];
            if constexpr (OFF >= 2) f[j][4] = p[4];
        }
    }
#pragma unroll
    for (int j = 0; j < 4; ++j) {
        uint4 lo, hi;
        if (wo >= 124) {
            lo = make_uint4(0u, 0u, 0u, 0u);
            hi = make_uint4(0u, 0u, 0u, 0u);
        } else {
            float w[20];
#pragma unroll
            for (int q = 0; q < 4; ++q) {
                w[4 * q] = f[j][q].x;
                w[4 * q + 1] = f[j][q].y;
                w[4 * q + 2] = f[j][q].z;
                w[4 * q + 3] = f[j][q].w;
            }
            if constexpr (OFF >= 2) {
                w[16] = f[j][4].x; w[17] = f[j][4].y;
                w[18] = f[j][4].z; w[19] = f[j][4].w;
            } else {
                w[16] = 0.f; w[17] = 0.f; w[18] = 0.f; w[19] = 0.f;
            }
            lo = make_uint4(pack2(w[OFF + 0], w[OFF + 1]),
                            pack2(w[OFF + 2], w[OFF + 3]),
                            pack2(w[OFF + 4], w[OFF + 5]),
                            pack2(w[OFF + 6], w[OFF + 7]));
            hi = make_uint4(pack2(w[OFF + 8], w[OFF + 9]),
                            pack2(w[OFF + 10], w[OFF + 11]),
                            pack2(w[OFF + 12], w[OFF + 13]),
                            pack2(w[OFF + 14], 0.0f));  // t=15: weight is zero
        }
        *reinterpret_cast<uint4*>((char*)s_im + im_off(rb + j, wo, 0)) = lo;
        *reinterpret_cast<uint4*>((char*)s_im + im_off(rb + j, wo, 1)) = hi;
    }
}

// ---------------- conv kernel: mu only (R6 structure + fixes) --------------
// 5 blocks/CU (LDS 5*32KB = 160KB exactly); load-first staging.
__global__ __launch_bounds__(256, 5) void conv_mu_kernel(
    const float* __restrict__ mu_in,
    const unsigned short* __restrict__ w_bf,
    float* __restrict__ mu_out) {

    __shared__ __align__(16) unsigned short s_im[8 * 128 * 16];  // 32 KB

    const int bid = xcd_swz(blockIdx.x);
    const int b = bid / NG;
    const int ho0 = (bid % NG) * 4;
    const int tid = threadIdx.x;
    const int lane = tid & 63;
    const int wid = tid >> 6;
    const int llo = lane & 15;
    const int lhi = lane >> 4;

    // weights -> regs (L2-hot)
    bfrag8 afr[4][3];
#pragma unroll
    for (int mt = 0; mt < 4; ++mt)
#pragma unroll
        for (int ks = 0; ks < 3; ++ks)
            afr[mt][ks] = *reinterpret_cast<const bfrag8*>(
                &w_bf[(mt * 16 + llo) * KP + ks * 32 + lhi * 8]);

    // im2col (each wave owns one wo mod-4 class)
    {
        const int wo = wid + ((lane & 31) << 2);
        switch (wid) {  // OFF = (3*class) mod 4
            case 0: im_stage<0>(mu_in, s_im, b, ho0, lane, wo); break;
            case 1: im_stage<3>(mu_in, s_im, b, ho0, lane, wo); break;
            case 2: im_stage<2>(mu_in, s_im, b, ho0, lane, wo); break;
            default: im_stage<1>(mu_in, s_im, b, ho0, lane, wo); break;
        }
    }
    __syncthreads();

#pragma unroll
    for (int hl = 0; hl < 4; ++hl) {
        ffrag4 acc[2][4];
#pragma unroll
        for (int nt = 0; nt < 2; ++nt)
#pragma unroll
            for (int mt = 0; mt < 4; ++mt)
                acc[nt][mt] = (ffrag4){0.f, 0.f, 0.f, 0.f};

#pragma unroll
        for (int nt = 0; nt < 2; ++nt) {
            const int wo = (wid * 2 + nt) * 16 + llo;
#pragma unroll
            for (int ks = 0; ks < 3; ++ks) {
                const int k0 = ks * 32 + lhi * 8;
                const int r = k0 >> 4;  // 0..5 (5 => k>=80: zero operand)
                bfrag8 bfr = (bfrag8){0, 0, 0, 0, 0, 0, 0, 0};
                if (r < 5) {
                    bfr = *reinterpret_cast<const bfrag8*>(
                        (char*)s_im + im_off(hl + r, wo, (k0 & 15) >> 3));
                }
#pragma unroll
                for (int mt = 0; mt < 4; ++mt)
                    acc[nt][mt] = __builtin_amdgcn_mfma_f32_16x16x32_bf16(
                        afr[mt][ks], bfr, acc[nt][mt], 0, 0, 0);
            }
        }

        const size_t orow = (size_t)(b * HO + ho0 + hl) * (size_t)(HO * KN);
#pragma unroll
        for (int nt = 0; nt < 2; ++nt) {
            const int wo = (wid * 2 + nt) * 16 + llo;
            if (wo < HO) {
                const size_t obase = orow + (size_t)wo * KN;
#pragma unroll
                for (int mt = 0; mt < 4; ++mt) {
                    const int knb = mt * 16 + lhi * 4;
                    *reinterpret_cast<float4*>(&mu_out[obase + knb]) =
                        make_float4(acc[nt][mt][0], acc[nt][mt][1],
                                    acc[nt][mt][2], acc[nt][mt][3]);
                }
            }
        }
    }
}

// ---------------- sigma kernel: fused ssn compute + streaming expand -------
// One block per (b, ho-group of 4): reads its 8 input rows, computes ssn in
// LDS, then writes 7936 contiguous float4 chunks (31 per thread, 1KB/wave).
__global__ __launch_bounds__(256) void sigma_kernel(
    const float* __restrict__ mu_in, const float* __restrict__ sp_in,
    float4* __restrict__ sig_out) {
    __shared__ __align__(16) float s_cs[8 * 128];
    __shared__ float s_ssn[4 * 128];

    const int bid = xcd_swz(blockIdx.x);
    const int b = bid / NG;
    const int ho0 = (bid % NG) * 4;
    const int tid = threadIdx.x;

    // phase 1: per-(row,col) channel sum-of-squares
    {
        const int r = tid >> 5;          // 0..7
        const int c4 = (tid & 31) << 2;  // 0..124
        const float* p = mu_in + ((size_t)(b * 128 + ho0 + r) * 384 + c4 * 3);
        float4 f0 = reinterpret_cast<const float4*>(p)[0];
        float4 f1 = reinterpret_cast<const float4*>(p)[1];
        float4 f2 = reinterpret_cast<const float4*>(p)[2];
        float4 cs;
        cs.x = f0.x * f0.x + f0.y * f0.y + f0.z * f0.z;
        cs.y = f0.w * f0.w + f1.x * f1.x + f1.y * f1.y;
        cs.z = f1.z * f1.z + f1.w * f1.w + f2.x * f2.x;
        cs.w = f2.y * f2.y + f2.z * f2.z + f2.w * f2.w;
        *reinterpret_cast<float4*>(&s_cs[r * 128 + c4]) = cs;
    }
    __syncthreads();

    // phase 2: ssn[hl][wo] = (5x5 window sum)/75
#pragma unroll
    for (int it = 0; it < 2; ++it) {
        const int idx = tid + it * 256;
        const int hl = idx >> 7, wo = idx & 127;
        float v = 0.f;
        if (wo < HO) {
            float s = 0.f;
#pragma unroll
            for (int r = 0; r < 5; ++r) {
                const float* cr = &s_cs[(hl + r) * 128 + wo];
                s += cr[0] + cr[1] + cr[2] + cr[3] + cr[4];
            }
            v = s * (1.0f / 75.0f);
        }
        s_ssn[idx] = v;
    }
    __syncthreads();

    // phase 3: stream 7936 contiguous chunks; q = tid&15 fixed per thread
    const float4 sp4 = reinterpret_cast<const float4*>(sp_in)[tid & 15];
    const size_t base = (size_t)(b * HO + ho0) * (HO * KN / 4);  // 1984/row
#pragma unroll
    for (int i = 0; i < 31; ++i) {
        const int c = tid + i * 256;        // 0..7935
        const int row = c / 1984;           // 0..3 (const-div -> magic mul)
        const int wo = (c - row * 1984) >> 4;
        const float s = s_ssn[row * 128 + wo];
        sig_out[base + c] =
            make_float4(sp4.x * s, sp4.y * s, sp4.z * s, sp4.w * s);
    }
}

extern "C" void kernel_launch(void* const* d_in, const int* in_sizes, int n_in,
                              void* d_out, int out_size, void* d_ws,
                              size_t ws_size, hipStream_t stream) {
    const float* mu_in = (const float*)d_in[0];
    const float* w_mu = (const float*)d_in[1];
    const float* w_sigma = (const float*)d_in[2];
    float* out = (float*)d_out;

    float* mu_out = out;             // N floats
    float* sig_out = out + NOUT;     // N floats
    float* kl_out = out + 2 * NOUT;  // 1 float

    char* ws = (char*)d_ws;
    unsigned short* w_bf = (unsigned short*)(ws + WS_WBF_OFF);
    float* sp_ws = (float*)(ws + WS_SP_OFF);

    prep_kernel<<<1, 256, 0, stream>>>(w_mu, w_sigma, w_bf, sp_ws, kl_out);
    conv_mu_kernel<<<NCONV, 256, 0, stream>>>(mu_in, w_bf, mu_out);
    sigma_kernel<<<NCONV, 256, 0, stream>>>(mu_in, sp_ws, (float4*)sig_out);
}

// Round 12
// 233.277 us; speedup vs baseline: 7.2569x; 1.2974x over previous
//
#include <hip/hip_runtime.h>
#include <hip/hip_bf16.h>
#include <math.h>

#define KN 64
#define HO 124
#define KP 104
#define NOUT (128LL * 124 * 124 * 64)  // 125,960,192
#define NG 31                          // ho-groups (of 4) per image
#define NCONV (128 * NG)               // 3968 conv blocks

// ws layout: ssn 7,872,512 B | w_bf 13,312 B | sp 256 B
#define WS_SSN_OFF 0ULL
#define WS_WBF_OFF 7872512ULL
#define WS_SP_OFF 7885824ULL

typedef short bfrag8 __attribute__((ext_vector_type(8)));  // 8 bf16
typedef float ffrag4 __attribute__((ext_vector_type(4)));  // 4 f32

__device__ __forceinline__ unsigned short f2bf(float f) {
    union { float f; unsigned u; } x;
    x.f = f;
    unsigned r = x.u + 0x7fffu + ((x.u >> 16) & 1u);
    return (unsigned short)(r >> 16);
}
__device__ __forceinline__ unsigned pack2(float a, float b) {
    return (unsigned)f2bf(a) | ((unsigned)f2bf(b) << 16);
}

// XOR-swizzled byte offset into s_im: [row][wo][16 bf16] = 32 B per (row,wo).
__device__ __forceinline__ int im_off(int row, int wo, int half) {
    return (((row * 128 + wo) * 32) + half * 16) ^ (((wo >> 2) & 7) << 4);
}

// -------- one-time prep: weight transpose->bf16 + softplus + KL scalar -----
__global__ void prep_kernel(const float* __restrict__ w_mu,
                            const float* __restrict__ w_sigma,
                            unsigned short* __restrict__ w_bf,
                            float* __restrict__ sp_out,
                            float* __restrict__ out_kl) {
    const int tid = threadIdx.x;       // 256
    const int n = tid >> 2;            // 64 rows, 4 threads each
    const int kbase = (tid & 3) * 26;  // 4*26 = 104
#pragma unroll
    for (int kk = 0; kk < 26; ++kk) {
        const int k = kbase + kk;
        float v = 0.f;
        if (k < 80) {
            const int r = k >> 4, t = k & 15;
            if (t < 15) v = w_mu[(r * 15 + t) * KN + n];
        }
        w_bf[n * KP + k] = f2bf(v);
    }
    if (tid < KN) sp_out[tid] = log1pf(expf(w_sigma[tid]));

    if (tid < 64) {
        float s = 0.f;
#pragma unroll
        for (int i = 0; i < 75; ++i) {
            float m = w_mu[i * KN + tid];
            s = fmaf(m, m, s);
        }
        float lv = w_sigma[tid];
        float sp = log1pf(expf(lv));
        float val = 1.0f + lv - sp - s * (1.0f / 75.0f);
#pragma unroll
        for (int off = 32; off > 0; off >>= 1) val += __shfl_down(val, off);
        if (tid == 0) {
            float kl = -(val / 64.0f);
            if (isnan(kl) || isinf(kl)) kl = 1e-5f;
            out_kl[0] = kl;
        }
    }
}

// ---------------- ssn prepass: patch sum-of-squares / 75 -------------------
__global__ void ssn_kernel(const float* __restrict__ mu_in,
                           float* __restrict__ ssn_ws) {
    __shared__ __align__(16) float s_cs[8 * 128];
    const int bid = blockIdx.x;
    const int b = bid / NG;
    const int ho0 = (bid % NG) * 4;
    const int tid = threadIdx.x;

    {
        const int r = tid >> 5;          // 0..7
        const int c4 = (tid & 31) << 2;  // 0..124
        const float* p = mu_in + ((size_t)(b * 128 + ho0 + r) * 384 + c4 * 3);
        float4 f0 = reinterpret_cast<const float4*>(p)[0];
        float4 f1 = reinterpret_cast<const float4*>(p)[1];
        float4 f2 = reinterpret_cast<const float4*>(p)[2];
        float4 cs;
        cs.x = f0.x * f0.x + f0.y * f0.y + f0.z * f0.z;
        cs.y = f0.w * f0.w + f1.x * f1.x + f1.y * f1.y;
        cs.z = f1.z * f1.z + f1.w * f1.w + f2.x * f2.x;
        cs.w = f2.y * f2.y + f2.z * f2.z + f2.w * f2.w;
        *reinterpret_cast<float4*>(&s_cs[r * 128 + c4]) = cs;
    }
    __syncthreads();

#pragma unroll
    for (int it = 0; it < 2; ++it) {
        const int idx = tid + it * 256;
        const int hl = idx >> 7, wo = idx & 127;
        if (wo < HO) {
            float s = 0.f;
#pragma unroll
            for (int r = 0; r < 5; ++r) {
                const float* cr = &s_cs[(hl + r) * 128 + wo];
                s += cr[0] + cr[1] + cr[2] + cr[3] + cr[4];
            }
            ssn_ws[((size_t)(b * HO) + ho0 + hl) * HO + wo] = s * (1.0f / 75.0f);
        }
    }
}

// ---------------- sigma streaming kernel (fill-like) -----------------------
__global__ __launch_bounds__(256) void sigma_kernel(
    const float* __restrict__ ssn_ws, const float* __restrict__ sp_in,
    float4* __restrict__ sig_out) {
    const long long TOT = 128LL * 124 * 124 * 16;  // 31,490,048 chunks
    const long long NT = (long long)gridDim.x * 256;
    const long long g0 = (long long)blockIdx.x * 256 + threadIdx.x;
    const float4 sp4 = reinterpret_cast<const float4*>(sp_in)[g0 & 15];

    long long g = g0;
    for (; g + 3 * NT < TOT; g += 4 * NT) {
        const float s0 = ssn_ws[g >> 4];
        const float s1 = ssn_ws[(g + NT) >> 4];
        const float s2 = ssn_ws[(g + 2 * NT) >> 4];
        const float s3 = ssn_ws[(g + 3 * NT) >> 4];
        sig_out[g] = make_float4(sp4.x * s0, sp4.y * s0, sp4.z * s0, sp4.w * s0);
        sig_out[g + NT] =
            make_float4(sp4.x * s1, sp4.y * s1, sp4.z * s1, sp4.w * s1);
        sig_out[g + 2 * NT] =
            make_float4(sp4.x * s2, sp4.y * s2, sp4.z * s2, sp4.w * s2);
        sig_out[g + 3 * NT] =
            make_float4(sp4.x * s3, sp4.y * s3, sp4.z * s3, sp4.w * s3);
    }
    for (; g < TOT; g += NT) {
        const float s = ssn_ws[g >> 4];
        sig_out[g] = make_float4(sp4.x * s, sp4.y * s, sp4.z * s, sp4.w * s);
    }
}

// im2col fill: wave-uniform alignment class. OFF = (3*wo) mod 4, constexpr.
// (R6 register-light version: per-row load->pack->write; VGPR ~64.)
template <int OFF>
__device__ __forceinline__ void im_fill(const float* __restrict__ mu_in,
                                        unsigned short* s_im, int b, int ho0,
                                        int lane, int wo) {
#pragma unroll
    for (int j = 0; j < 4; ++j) {
        const int row = ((lane >> 5) << 2) + j;  // 0..7
        uint4* dst0 =
            reinterpret_cast<uint4*>((char*)s_im + im_off(row, wo, 0));
        uint4* dst1 =
            reinterpret_cast<uint4*>((char*)s_im + im_off(row, wo, 1));
        if (wo >= 124) {
            *dst0 = make_uint4(0u, 0u, 0u, 0u);
            *dst1 = make_uint4(0u, 0u, 0u, 0u);
            continue;
        }
        const float* p =
            mu_in + ((size_t)(b * 128 + ho0 + row) * 384 + wo * 3 - OFF);
        float w[20];
        float4 f;
        f = reinterpret_cast<const float4*>(p)[0];
        w[0] = f.x; w[1] = f.y; w[2] = f.z; w[3] = f.w;
        f = reinterpret_cast<const float4*>(p)[1];
        w[4] = f.x; w[5] = f.y; w[6] = f.z; w[7] = f.w;
        f = reinterpret_cast<const float4*>(p)[2];
        w[8] = f.x; w[9] = f.y; w[10] = f.z; w[11] = f.w;
        f = reinterpret_cast<const float4*>(p)[3];
        w[12] = f.x; w[13] = f.y; w[14] = f.z; w[15] = f.w;
        if (OFF >= 2) {
            f = reinterpret_cast<const float4*>(p)[4];
            w[16] = f.x; w[17] = f.y; w[18] = f.z; w[19] = f.w;
        } else {
            w[16] = 0.f; w[17] = 0.f; w[18] = 0.f; w[19] = 0.f;
        }
        unsigned u0 = pack2(w[OFF + 0], w[OFF + 1]);
        unsigned u1 = pack2(w[OFF + 2], w[OFF + 3]);
        unsigned u2 = pack2(w[OFF + 4], w[OFF + 5]);
        unsigned u3 = pack2(w[OFF + 6], w[OFF + 7]);
        unsigned u4 = pack2(w[OFF + 8], w[OFF + 9]);
        unsigned u5 = pack2(w[OFF + 10], w[OFF + 11]);
        unsigned u6 = pack2(w[OFF + 12], w[OFF + 13]);
        unsigned u7 = pack2(w[OFF + 14], 0.0f);  // t=15: weight is zero
        *dst0 = make_uint4(u0, u1, u2, u3);
        *dst1 = make_uint4(u4, u5, u6, u7);
    }
}

// ---------------- conv kernel: mu only, full-line store epilogue -----------
// R6 structure; ONLY change: C-tile round-trips a private 4KB/wave LDS
// scratch so each global store instruction writes 1KB contiguous (full 128B
// lines -> no RFO fetch; R10 PMC showed FETCH ~= output size from 64B
// partial-line writes). LDS 32+16=48KB -> 3 blocks/CU.
__global__ __launch_bounds__(256, 3) void conv_mu_kernel(
    const float* __restrict__ mu_in,
    const unsigned short* __restrict__ w_bf,
    float* __restrict__ mu_out) {

    __shared__ __align__(16) unsigned short s_im[8 * 128 * 16];  // 32 KB
    __shared__ __align__(16) char s_ep[4 * 4096];                // 16 KB

    const int bid = blockIdx.x;
    const int b = bid / NG;
    const int ho0 = (bid % NG) * 4;
    const int tid = threadIdx.x;
    const int lane = tid & 63;
    const int wid = tid >> 6;
    const int llo = lane & 15;
    const int lhi = lane >> 4;

    // weights -> regs (L2-hot)
    bfrag8 afr[4][3];
#pragma unroll
    for (int mt = 0; mt < 4; ++mt)
#pragma unroll
        for (int ks = 0; ks < 3; ++ks)
            afr[mt][ks] = *reinterpret_cast<const bfrag8*>(
                &w_bf[(mt * 16 + llo) * KP + ks * 32 + lhi * 8]);

    // im2col (each wave owns one wo mod-4 class)
    {
        const int wo = wid + ((lane & 31) << 2);
        switch (wid) {  // OFF = (3*class) mod 4
            case 0: im_fill<0>(mu_in, s_im, b, ho0, lane, wo); break;
            case 1: im_fill<3>(mu_in, s_im, b, ho0, lane, wo); break;
            case 2: im_fill<2>(mu_in, s_im, b, ho0, lane, wo); break;
            default: im_fill<1>(mu_in, s_im, b, ho0, lane, wo); break;
        }
    }
    __syncthreads();

    char* sep = s_ep + wid * 4096;  // wave-private scratch (no cross-wave use)

#pragma unroll
    for (int hl = 0; hl < 4; ++hl) {
        ffrag4 acc[2][4];
#pragma unroll
        for (int nt = 0; nt < 2; ++nt)
#pragma unroll
            for (int mt = 0; mt < 4; ++mt)
                acc[nt][mt] = (ffrag4){0.f, 0.f, 0.f, 0.f};

#pragma unroll
        for (int nt = 0; nt < 2; ++nt) {
            const int wo = (wid * 2 + nt) * 16 + llo;
#pragma unroll
            for (int ks = 0; ks < 3; ++ks) {
                const int k0 = ks * 32 + lhi * 8;
                const int r = k0 >> 4;  // 0..5 (5 => k>=80: zero operand)
                bfrag8 bfr = (bfrag8){0, 0, 0, 0, 0, 0, 0, 0};
                if (r < 5) {
                    bfr = *reinterpret_cast<const bfrag8*>(
                        (char*)s_im + im_off(hl + r, wo, (k0 & 15) >> 3));
                }
#pragma unroll
                for (int mt = 0; mt < 4; ++mt)
                    acc[nt][mt] = __builtin_amdgcn_mfma_f32_16x16x32_bf16(
                        afr[mt][ks], bfr, acc[nt][mt], 0, 0, 0);
            }
        }

        const size_t orow = (size_t)(b * HO + ho0 + hl) * (size_t)(HO * KN);
#pragma unroll
        for (int nt = 0; nt < 2; ++nt) {
            // scratch layout [p][q] (pixel p = wo-local 0..15, kn-quad q),
            // byte = p*256 + q*16, XOR-swizzled by ((p&7)<<4): 8 lanes per
            // 4-bank group on both sides = optimal for b128.
#pragma unroll
            for (int mt = 0; mt < 4; ++mt) {
                const int sb = (llo * 256 + (mt * 4 + lhi) * 16) ^
                               ((llo & 7) << 4);
                *reinterpret_cast<ffrag4*>(sep + sb) = acc[nt][mt];
            }
            asm volatile("s_waitcnt lgkmcnt(0)" ::: "memory");

            const int wo0 = (wid * 2 + nt) * 16;
            float* gp = mu_out + orow + (size_t)wo0 * KN;
#pragma unroll
            for (int c = 0; c < 4; ++c) {
                if (wo0 + c * 4 < HO) {  // skips only wid3,nt1,c3 (wo 124..)
                    const int p = c * 4 + lhi;
                    const int rb = (p * 256 + llo * 16) ^ ((p & 7) << 4);
                    const float4 v = *reinterpret_cast<const float4*>(sep + rb);
                    // contiguous 1KB per wave-instruction: full 128B lines
                    *reinterpret_cast<float4*>(gp + c * 256 + lane * 4) = v;
                }
            }
            asm volatile("s_waitcnt lgkmcnt(0)" ::: "memory");  // reads done
        }
    }
}

extern "C" void kernel_launch(void* const* d_in, const int* in_sizes, int n_in,
                              void* d_out, int out_size, void* d_ws,
                              size_t ws_size, hipStream_t stream) {
    const float* mu_in = (const float*)d_in[0];
    const float* w_mu = (const float*)d_in[1];
    const float* w_sigma = (const float*)d_in[2];
    float* out = (float*)d_out;

    float* mu_out = out;             // N floats
    float* sig_out = out + NOUT;     // N floats
    float* kl_out = out + 2 * NOUT;  // 1 float

    char* ws = (char*)d_ws;
    float* ssn_ws = (float*)(ws + WS_SSN_OFF);
    unsigned short* w_bf = (unsigned short*)(ws + WS_WBF_OFF);
    float* sp_ws = (float*)(ws + WS_SP_OFF);

    prep_kernel<<<1, 256, 0, stream>>>(w_mu, w_sigma, w_bf, sp_ws, kl_out);
    ssn_kernel<<<128 * NG, 256, 0, stream>>>(mu_in, ssn_ws);
    conv_mu_kernel<<<NCONV, 256, 0, stream>>>(mu_in, w_bf, mu_out);
    sigma_kernel<<<2048, 256, 0, stream>>>(ssn_ws, sp_ws, (float4*)sig_out);
}